// Round 8
// baseline (51.837 us; speedup 1.0000x reference)
//
#include <hip/hip_runtime.h>

// Problem constants (match reference)
#define N_NODES 4096
#define N_EDGES 131072
#define D_FEAT  512
#define K_SEL   2048      // ceil(0.5 * 4096)
#define MAXDEG  128       // slot capacity per node (mean deg 32, max ~55; verified <=128 by absmax=0 across R5-R7)
#define NWORDS  128       // 4096 bits / 32
#define OWN     32        // nodes owned per bss block
#define NBSS    (N_NODES / OWN)   // 128 blocks

// ---------------- stage 1: build+score fused (ownership scan, v4) ----------------
// 128 blocks x 1024 threads (4 waves/SIMD on every active CU -> latency hidden).
// Each block owns 32 nodes and streams src[] as int4 (32 iters/thread, ~64 MB
// aggregate L2 traffic = half of R7's). dst4 fetched only when the int4 contains
// an owned edge. LDS slot lists via LDS atomics (no global zeroing dispatch, no
// global atomics). Then each wave scores 2 nodes (w, w+16): exact in-wave rank by
// packed key (eidx<<12|dst) restores original edge order for the bit-exact
// sequential fp32 attention sum. Writes cnt/slots/scores (adj reads slots).
__global__ __launch_bounds__(1024) void bss_kernel(
    const int* __restrict__ src, const int* __restrict__ dst,
    const float* __restrict__ att, const int* __restrict__ dir_p,
    unsigned* __restrict__ cnt, unsigned* __restrict__ gslots,
    float* __restrict__ scores)
{
    __shared__ unsigned lcnt[OWN];
    __shared__ unsigned lslots[OWN][MAXDEG];   // 16 KiB
    __shared__ float    a_ord[OWN][MAXDEG];    // 16 KiB
    const int t = threadIdx.x;
    const int wave = t >> 6, lane = t & 63;
    const int base = blockIdx.x * OWN;

    if (t < OWN) lcnt[t] = 0u;
    __syncthreads();

    // ---- ownership scan: 32768 int4 / 1024 threads = 32 iters ----
    const int4* s4 = (const int4*)src;
    const int4* d4 = (const int4*)dst;
    for (int i = t; i < N_EDGES / 4; i += 1024) {
        int4 v = s4[i];
        unsigned m0 = (unsigned)(v.x - base);
        unsigned m1 = (unsigned)(v.y - base);
        unsigned m2 = (unsigned)(v.z - base);
        unsigned m3 = (unsigned)(v.w - base);
        if ((m0 < OWN) | (m1 < OWN) | (m2 < OWN) | (m3 < OWN)) {
            int4 w4 = d4[i];                  // fetched only on match (rare)
            int e0 = i << 2;
            if (m0 < OWN) { unsigned p = atomicAdd(&lcnt[m0], 1u);
                if (p < MAXDEG) lslots[m0][p] = ((unsigned)(e0 + 0) << 12) | (unsigned)w4.x; }
            if (m1 < OWN) { unsigned p = atomicAdd(&lcnt[m1], 1u);
                if (p < MAXDEG) lslots[m1][p] = ((unsigned)(e0 + 1) << 12) | (unsigned)w4.y; }
            if (m2 < OWN) { unsigned p = atomicAdd(&lcnt[m2], 1u);
                if (p < MAXDEG) lslots[m2][p] = ((unsigned)(e0 + 2) << 12) | (unsigned)w4.z; }
            if (m3 < OWN) { unsigned p = atomicAdd(&lcnt[m3], 1u);
                if (p < MAXDEG) lslots[m3][p] = ((unsigned)(e0 + 3) << 12) | (unsigned)w4.w; }
        }
    }
    __syncthreads();

    // ---- score: wave w handles nodes base+w and base+w+16 ----
    #pragma unroll
    for (int half = 0; half < 2; ++half) {
        int ln = wave + (half << 4);           // node-local index, wave-private
        int n = base + ln;
        unsigned d = min(lcnt[ln], (unsigned)MAXDEG);
        unsigned v0 = (lane < (int)d)        ? lslots[ln][lane]      : 0xFFFFFFFFu;
        unsigned v1 = ((lane + 64) < (int)d) ? lslots[ln][lane + 64] : 0xFFFFFFFFu;

        // issue att gathers early (latency hides under the rank loop)
        float a0 = (lane < (int)d)        ? att[v0 >> 12] : 0.0f;
        float a1 = ((lane + 64) < (int)d) ? att[v1 >> 12] : 0.0f;

        // exact in-wave rank by packed key (== rank by edge index)
        int r0 = 0, r1 = 0;
        int dk = (d < 64u) ? (int)d : 64;      // wave-uniform bound
        if (d <= 64u) {
            for (int k = 0; k < dk; ++k) {
                unsigned a = __shfl(v0, k);
                r0 += (a < v0);
            }
        } else {
            for (int k = 0; k < dk; ++k) {
                unsigned a = __shfl(v0, k);
                unsigned b = __shfl(v1, k);
                r0 += (a < v0) + (b < v0);
                r1 += (a < v1) + (b < v1);
            }
        }
        if (lane < (int)d)        a_ord[ln][r0] = a0;
        if ((lane + 64) < (int)d) a_ord[ln][r1] = a1;
        // a_ord[ln] is wave-private; wave-synchronous LDS write->read (compiler
        // inserts lgkmcnt), no block barrier needed.

        if (lane == 0) {
            float sum = 0.0f;
            unsigned i = 0;
            for (; i + 4 <= d; i += 4) {       // float4 LDS loads, scalar-ordered adds
                float4 q = *(const float4*)&a_ord[ln][i];
                sum += q.x; sum += q.y; sum += q.z; sum += q.w;
            }
            for (; i < d; ++i) sum += a_ord[ln][i];
            float score = 0.0f;
            if (d > 0) {
                float df = (float)d;
                float mean = sum / df;                  // fl(att_sum / degree)
                score = ((float)dir_p[0] * mean) * df;  // (direction * att_mean) * degree
            }
            scores[n] = score;
            cnt[n] = d;
        }
        // coalesced global slot writes (valid prefix only; adj reads [0,d))
        unsigned nb = (unsigned)n << 7;
        if (lane < (int)d)        gslots[nb + lane] = v0;
        if ((lane + 64) < (int)d) gslots[nb + lane + 64] = v1;
    }
}

// ---------------- stage 2: exact stable descending rank + fused x gather ----------------
__global__ void rank_kernel(const float* __restrict__ scores,
                            const int* __restrict__ batch,
                            const float* __restrict__ x,
                            unsigned* __restrict__ permw,
                            float* __restrict__ out_x,
                            float* __restrict__ out_batch,
                            float* __restrict__ out_perm) {
    int t = threadIdx.x, wave = t >> 6, lane = t & 63;
    int n = blockIdx.x * 4 + wave;       // 1024 blocks x 4 waves
    float s = scores[n];
    const float4* sc4 = (const float4*)scores;
    int r = 0;
    #pragma unroll
    for (int i = 0; i < 16; ++i) {
        int q = lane + (i << 6);         // float4 index, coalesced, cache-resident
        float4 v = sc4[q];
        int m = q << 2;
        r += (v.x > s) || (v.x == s && (m + 0) < n);
        r += (v.y > s) || (v.y == s && (m + 1) < n);
        r += (v.z > s) || (v.z == s && (m + 2) < n);
        r += (v.w > s) || (v.w == s && (m + 3) < n);
    }
    #pragma unroll
    for (int off = 32; off; off >>= 1) r += __shfl_down(r, off);
    r = __shfl(r, 0);                    // broadcast rank to all lanes
    if (r < K_SEL) {
        if (lane == 0) {
            permw[r] = (unsigned)n;
            out_perm[r] = (float)n;
            out_batch[r] = (float)batch[n];
        }
        // whole wave copies the selected x row: 512 floats = 128 float4
        const float4* xs = (const float4*)(x + (size_t)n * D_FEAT);
        float4* od = (float4*)(out_x + (size_t)r * D_FEAT);
        od[lane] = xs[lane];
        od[lane + 64] = xs[lane + 64];
    }
}

// ---------------- stage 3: 2-hop adjacency directly from slot lists ----------------
// row(n) = union over m in nbr(n) of dst-set(m). Reads neighbors' slot rows
// (coalesced) and scatters bits into an LDS row via atomicOr.
__global__ void adj_kernel(const unsigned* __restrict__ permw,
                           const unsigned* __restrict__ cnt,
                           const unsigned* __restrict__ slots,
                           float* __restrict__ out_adj) {
    __shared__ unsigned nbr[MAXDEG];
    __shared__ unsigned dnb[MAXDEG];
    __shared__ unsigned row[NWORDS];
    int p = blockIdx.x, t = threadIdx.x;   // 256 threads
    unsigned n = permw[p];
    unsigned d = min(cnt[n], (unsigned)MAXDEG);
    if (t < NWORDS) row[t] = 0u;
    if (t < (int)d) {
        unsigned m = slots[((size_t)n << 7) + t] & 0xFFFu;
        nbr[t] = m;
        dnb[t] = cnt[m];                   // <= MAXDEG by construction
    }
    __syncthreads();
    // two neighbors per iteration: h = which neighbor, w = entry index
    int w = t & 127, h = t >> 7;
    for (unsigned i = (unsigned)h; i < d; i += 2) {
        if (w < (int)dnb[i]) {
            unsigned dv = slots[((size_t)nbr[i] << 7) + w] & 0xFFFu;   // coalesced
            atomicOr(&row[dv >> 5], 1u << (dv & 31));
        }
    }
    __syncthreads();
    float4* o4 = (float4*)(out_adj + (size_t)p * K_SEL);
    #pragma unroll
    for (int i = 0; i < 2; ++i) {
        int q4 = t + (i << 8);             // 512 float4 per row
        int q = q4 << 2;
        unsigned c0 = permw[q], c1 = permw[q + 1], c2 = permw[q + 2], c3 = permw[q + 3];
        float4 v;
        v.x = (float)((row[c0 >> 5] >> (c0 & 31)) & 1u);
        v.y = (float)((row[c1 >> 5] >> (c1 & 31)) & 1u);
        v.z = (float)((row[c2 >> 5] >> (c2 & 31)) & 1u);
        v.w = (float)((row[c3 >> 5] >> (c3 & 31)) & 1u);
        o4[q4] = v;
    }
}

extern "C" void kernel_launch(void* const* d_in, const int* in_sizes, int n_in,
                              void* d_out, int out_size, void* d_ws, size_t ws_size,
                              hipStream_t stream) {
    const float* x     = (const float*)d_in[0];
    const int*   eidx  = (const int*)d_in[1];
    const float* att   = (const float*)d_in[2];
    const int*   batch = (const int*)d_in[3];
    const int*   dir_p = (const int*)d_in[4];
    const int* src = eidx;
    const int* dst = eidx + N_EDGES;

    // workspace layout (bytes)
    char* ws = (char*)d_ws;
    unsigned* cnt    = (unsigned*)(ws + 0);        // 16,384
    float*    scores = (float*)   (ws + 16384);    // 16,384
    unsigned* permw  = (unsigned*)(ws + 32768);    // 8,192
    unsigned* gslots = (unsigned*)(ws + 40960);    // 2,097,152 (end ~2.1 MB)

    // output layout (floats)
    float* out_x     = (float*)d_out;                          // 2048*512
    float* out_adj   = out_x + (size_t)K_SEL * D_FEAT;         // 2048*2048
    float* out_batch = out_adj + (size_t)K_SEL * K_SEL;        // 2048
    float* out_perm  = out_batch + K_SEL;                      // 2048

    bss_kernel<<<NBSS, 1024, 0, stream>>>(src, dst, att, dir_p, cnt, gslots, scores);
    rank_kernel<<<N_NODES / 4, 256, 0, stream>>>(scores, batch, x, permw,
                                                 out_x, out_batch, out_perm);
    adj_kernel<<<K_SEL, 256, 0, stream>>>(permw, cnt, gslots, out_adj);
}

// Round 9
// 46.082 us; speedup vs baseline: 1.1249x; 1.1249x over previous
//
#include <hip/hip_runtime.h>

// Problem constants (match reference)
#define N_NODES 4096
#define N_EDGES 131072
#define D_FEAT  512
#define K_SEL   2048      // ceil(0.5 * 4096)
#define MAXDEG  128       // slot capacity per node (mean deg 32, max ~55; absmax=0 across R5-R8)
#define NWORDS  128       // 4096 bits / 32

// ---------------- stage 0: zero cnt (16 KB) ----------------
__global__ void zero_cnt(unsigned* __restrict__ cnt) {
    cnt[blockIdx.x * 256 + threadIdx.x] = 0u;
}

// ---------------- stage 1: build per-node slot lists (unordered) ----------------
// slots[s][pos] = (eidx << 12) | dst  — eidx fits 17 bits, dst fits 12 bits.
// atomicAdd order is nondeterministic but all consumers are order-independent
// (score re-ranks by eidx; adj is a set-union) -> outputs deterministic.
__global__ void build_kernel(const int* __restrict__ src, const int* __restrict__ dst,
                             unsigned* __restrict__ cnt, unsigned* __restrict__ slots) {
    int e = blockIdx.x * 512 + threadIdx.x;
    int s = src[e];
    int d = dst[e];
    unsigned pos = atomicAdd(&cnt[s], 1u);
    if (pos < MAXDEG) slots[((unsigned)s << 7) + pos] = ((unsigned)e << 12) | (unsigned)d;
}

// ---------------- stage 2: score; ONE WAVE per node, exact edge-order fp32 sum ----------------
// Read-only on slots. Exact in-wave rank by packed key (eidx<<12|dst) restores the
// original edge order; lane 0 then sums sequentially -> bit-identical to the
// reference's in-order segment_sum.
__global__ void score_kernel(const unsigned* __restrict__ cnt,
                             const unsigned* __restrict__ slots,
                             const float* __restrict__ att,
                             const int* __restrict__ dir_p,
                             float* __restrict__ scores) {
    __shared__ float a_ord[4][MAXDEG];     // 2 KiB
    int t = threadIdx.x, wave = t >> 6, lane = t & 63;
    int n = blockIdx.x * 4 + wave;         // 1024 blocks x 4 waves = 4096 nodes
    unsigned nb = (unsigned)n << 7;
    unsigned d = min(cnt[n], (unsigned)MAXDEG);
    unsigned v0 = (lane < (int)d)        ? slots[nb + lane]      : 0xFFFFFFFFu;
    unsigned v1 = ((lane + 64) < (int)d) ? slots[nb + lane + 64] : 0xFFFFFFFFu;

    // issue att gathers early (latency hides under the rank loop)
    float a0 = (lane < (int)d)        ? att[v0 >> 12] : 0.0f;
    float a1 = ((lane + 64) < (int)d) ? att[v1 >> 12] : 0.0f;

    // exact in-wave rank by packed key (== rank by edge index)
    int r0 = 0, r1 = 0;
    int dk = (d < 64u) ? (int)d : 64;      // wave-uniform bound
    if (d <= 64u) {
        for (int k = 0; k < dk; ++k) {
            unsigned a = __shfl(v0, k);
            r0 += (a < v0);
        }
    } else {
        for (int k = 0; k < dk; ++k) {
            unsigned a = __shfl(v0, k);
            unsigned b = __shfl(v1, k);
            r0 += (a < v0) + (b < v0);
            r1 += (a < v1) + (b < v1);
        }
    }
    if (lane < (int)d)        a_ord[wave][r0] = a0;
    if ((lane + 64) < (int)d) a_ord[wave][r1] = a1;
    __syncthreads();                       // order LDS writes before lane0 reads

    if (lane == 0) {
        float sum = 0.0f;
        unsigned i = 0;
        for (; i + 4 <= d; i += 4) {       // float4 LDS loads, scalar-ordered adds
            float4 q = *(const float4*)&a_ord[wave][i];
            sum += q.x; sum += q.y; sum += q.z; sum += q.w;
        }
        for (; i < d; ++i) sum += a_ord[wave][i];
        float score = 0.0f;
        if (d > 0) {
            float df = (float)d;
            float mean = sum / df;                  // fl(att_sum / degree)
            score = ((float)dir_p[0] * mean) * df;  // (direction * att_mean) * degree
        }
        scores[n] = score;
    }
}

// ---------------- stage 3: exact stable descending rank + fused x gather ----------------
__global__ void rank_kernel(const float* __restrict__ scores,
                            const int* __restrict__ batch,
                            const float* __restrict__ x,
                            unsigned* __restrict__ permw,
                            float* __restrict__ out_x,
                            float* __restrict__ out_batch,
                            float* __restrict__ out_perm) {
    int t = threadIdx.x, wave = t >> 6, lane = t & 63;
    int n = blockIdx.x * 4 + wave;       // 1024 blocks x 4 waves
    float s = scores[n];
    const float4* sc4 = (const float4*)scores;
    int r = 0;
    #pragma unroll
    for (int i = 0; i < 16; ++i) {
        int q = lane + (i << 6);         // float4 index, coalesced, cache-resident
        float4 v = sc4[q];
        int m = q << 2;
        r += (v.x > s) || (v.x == s && (m + 0) < n);
        r += (v.y > s) || (v.y == s && (m + 1) < n);
        r += (v.z > s) || (v.z == s && (m + 2) < n);
        r += (v.w > s) || (v.w == s && (m + 3) < n);
    }
    #pragma unroll
    for (int off = 32; off; off >>= 1) r += __shfl_down(r, off);
    r = __shfl(r, 0);                    // broadcast rank to all lanes
    if (r < K_SEL) {
        if (lane == 0) {
            permw[r] = (unsigned)n;
            out_perm[r] = (float)n;
            out_batch[r] = (float)batch[n];
        }
        // whole wave copies the selected x row: 512 floats = 128 float4
        const float4* xs = (const float4*)(x + (size_t)n * D_FEAT);
        float4* od = (float4*)(out_x + (size_t)r * D_FEAT);
        od[lane] = xs[lane];
        od[lane + 64] = xs[lane + 64];
    }
}

// ---------------- stage 4: 2-hop adjacency directly from slot lists ----------------
// row(n) = union over m in nbr(n) of dst-set(m). Reads neighbors' slot rows
// (coalesced) and scatters bits into an LDS row via atomicOr. No B bitset array.
__global__ void adj_kernel(const unsigned* __restrict__ permw,
                           const unsigned* __restrict__ cnt,
                           const unsigned* __restrict__ slots,
                           float* __restrict__ out_adj) {
    __shared__ unsigned nbr[MAXDEG];
    __shared__ unsigned dnb[MAXDEG];
    __shared__ unsigned row[NWORDS];
    int p = blockIdx.x, t = threadIdx.x;   // 256 threads
    unsigned n = permw[p];
    unsigned d = min(cnt[n], (unsigned)MAXDEG);
    if (t < NWORDS) row[t] = 0u;
    if (t < (int)d) {
        unsigned m = slots[((size_t)n << 7) + t] & 0xFFFu;
        nbr[t] = m;
        dnb[t] = min(cnt[m], (unsigned)MAXDEG);
    }
    __syncthreads();
    // two neighbors per iteration: h = which neighbor, w = entry index
    int w = t & 127, h = t >> 7;
    for (unsigned i = (unsigned)h; i < d; i += 2) {
        if (w < (int)dnb[i]) {
            unsigned dv = slots[((size_t)nbr[i] << 7) + w] & 0xFFFu;   // coalesced
            atomicOr(&row[dv >> 5], 1u << (dv & 31));
        }
    }
    __syncthreads();
    float4* o4 = (float4*)(out_adj + (size_t)p * K_SEL);
    #pragma unroll
    for (int i = 0; i < 2; ++i) {
        int q4 = t + (i << 8);             // 512 float4 per row
        int q = q4 << 2;
        unsigned c0 = permw[q], c1 = permw[q + 1], c2 = permw[q + 2], c3 = permw[q + 3];
        float4 v;
        v.x = (float)((row[c0 >> 5] >> (c0 & 31)) & 1u);
        v.y = (float)((row[c1 >> 5] >> (c1 & 31)) & 1u);
        v.z = (float)((row[c2 >> 5] >> (c2 & 31)) & 1u);
        v.w = (float)((row[c3 >> 5] >> (c3 & 31)) & 1u);
        o4[q4] = v;
    }
}

extern "C" void kernel_launch(void* const* d_in, const int* in_sizes, int n_in,
                              void* d_out, int out_size, void* d_ws, size_t ws_size,
                              hipStream_t stream) {
    const float* x     = (const float*)d_in[0];
    const int*   eidx  = (const int*)d_in[1];
    const float* att   = (const float*)d_in[2];
    const int*   batch = (const int*)d_in[3];
    const int*   dir_p = (const int*)d_in[4];
    const int* src = eidx;
    const int* dst = eidx + N_EDGES;

    // workspace layout (bytes)
    char* ws = (char*)d_ws;
    unsigned* cnt    = (unsigned*)(ws + 0);        // 16,384
    float*    scores = (float*)   (ws + 16384);    // 16,384
    unsigned* permw  = (unsigned*)(ws + 32768);    // 8,192
    unsigned* slots  = (unsigned*)(ws + 40960);    // 2,097,152 (end ~2.1 MB)

    // output layout (floats)
    float* out_x     = (float*)d_out;                          // 2048*512
    float* out_adj   = out_x + (size_t)K_SEL * D_FEAT;         // 2048*2048
    float* out_batch = out_adj + (size_t)K_SEL * K_SEL;        // 2048
    float* out_perm  = out_batch + K_SEL;                      // 2048

    zero_cnt<<<N_NODES / 256, 256, 0, stream>>>(cnt);
    build_kernel<<<N_EDGES / 512, 512, 0, stream>>>(src, dst, cnt, slots);
    score_kernel<<<N_NODES / 4, 256, 0, stream>>>(cnt, slots, att, dir_p, scores);
    rank_kernel<<<N_NODES / 4, 256, 0, stream>>>(scores, batch, x, permw,
                                                 out_x, out_batch, out_perm);
    adj_kernel<<<K_SEL, 256, 0, stream>>>(permw, cnt, slots, out_adj);
}

// Round 10
// 44.245 us; speedup vs baseline: 1.1716x; 1.0415x over previous
//
#include <hip/hip_runtime.h>

// Problem constants (match reference)
#define N_NODES 4096
#define N_EDGES 131072
#define D_FEAT  512
#define K_SEL   2048      // ceil(0.5 * 4096)
#define MAXDEG  128       // slot capacity per node (mean deg 32, max ~55; absmax=0 across R5-R9)
#define NWORDS  128       // 4096 bits / 32

// ---------------- stage 0: zero cnt only (16 KB) ----------------
__global__ void zero_cnt(unsigned* __restrict__ cnt) {
    cnt[blockIdx.x * 256 + threadIdx.x] = 0u;
}

// ---------------- stage 1: build per-node slot lists (unordered) ----------------
// slots[s][pos] = (eidx << 12) | dst  — eidx fits 17 bits, dst fits 12 bits.
// atomicAdd order is nondeterministic but all consumers are order-independent
// (score re-ranks by eidx; bitsets are ORs) -> outputs deterministic.
__global__ void build_kernel(const int* __restrict__ src, const int* __restrict__ dst,
                             unsigned* __restrict__ cnt, unsigned* __restrict__ slots) {
    int e = blockIdx.x * 512 + threadIdx.x;
    int s = src[e];
    int d = dst[e];
    unsigned pos = atomicAdd(&cnt[s], 1u);
    if (pos < MAXDEG) slots[((unsigned)s << 7) + pos] = ((unsigned)e << 12) | (unsigned)d;
}

// ---------------- stage 2: score (exact edge-order fp32 sum) + B bitset row ----------------
// One WAVE per node. The wave holds all the node's packed (eidx,dst) entries, so it
// both re-sorts attention into edge order AND constructs the full 512B out-neighbor
// bitset row in LDS -> coalesced write (B needs no pre-zero, no global atomics).
__global__ void score_kernel(const unsigned* __restrict__ cnt,
                             const unsigned* __restrict__ slots,
                             const float* __restrict__ att,
                             const int* __restrict__ dir_p,
                             float* __restrict__ scores,
                             unsigned* __restrict__ B) {
    __shared__ float a_ord[4][MAXDEG];     // 2 KiB
    __shared__ unsigned brow[4][NWORDS];   // 2 KiB
    int t = threadIdx.x, wave = t >> 6, lane = t & 63;
    int n = blockIdx.x * 4 + wave;         // 1024 blocks x 4 waves = 4096 nodes
    unsigned nb = (unsigned)n << 7;
    unsigned d = min(cnt[n], (unsigned)MAXDEG);
    // load up to 2 packed keys per lane; invalid -> UINT_MAX (sorts last, never used)
    unsigned v0 = (lane < (int)d)        ? slots[nb + lane]      : 0xFFFFFFFFu;
    unsigned v1 = ((lane + 64) < (int)d) ? slots[nb + lane + 64] : 0xFFFFFFFFu;

    // issue att gathers early (latency hides under the rank loop)
    float a0 = (lane < (int)d)        ? att[v0 >> 12] : 0.0f;
    float a1 = ((lane + 64) < (int)d) ? att[v1 >> 12] : 0.0f;

    // ---- bitset row (wave-private LDS, no block sync needed) ----
    brow[wave][lane] = 0u;
    brow[wave][lane + 64] = 0u;
    if (lane < (int)d)        atomicOr(&brow[wave][(v0 & 0xFFFu) >> 5], 1u << (v0 & 31));
    if ((lane + 64) < (int)d) atomicOr(&brow[wave][(v1 & 0xFFFu) >> 5], 1u << (v1 & 31));

    // ---- exact in-wave rank by packed key (== rank by edge index) ----
    int r0 = 0, r1 = 0;
    int dk = (d < 64u) ? (int)d : 64;      // wave-uniform bound
    if (d <= 64u) {
        for (int k = 0; k < dk; ++k) {
            unsigned a = __shfl(v0, k);
            r0 += (a < v0);
        }
    } else {
        for (int k = 0; k < dk; ++k) {
            unsigned a = __shfl(v0, k);
            unsigned b = __shfl(v1, k);
            r0 += (a < v0) + (b < v0);
            r1 += (a < v1) + (b < v1);
        }
    }
    if (lane < (int)d)        a_ord[wave][r0] = a0;
    if ((lane + 64) < (int)d) a_ord[wave][r1] = a1;
    __syncthreads();

    // coalesced B-row write (512B per wave)
    B[nb + lane] = brow[wave][lane];
    B[nb + lane + 64] = brow[wave][lane + 64];

    if (lane == 0) {
        float sum = 0.0f;
        unsigned i = 0;
        for (; i + 4 <= d; i += 4) {       // float4 LDS loads, scalar-ordered adds
            float4 q = *(const float4*)&a_ord[wave][i];
            sum += q.x; sum += q.y; sum += q.z; sum += q.w;
        }
        for (; i < d; ++i) sum += a_ord[wave][i];
        float score = 0.0f;
        if (d > 0) {
            float df = (float)d;
            float mean = sum / df;                  // fl(att_sum / degree)
            score = ((float)dir_p[0] * mean) * df;  // (direction * att_mean) * degree
        }
        scores[n] = score;
    }
}

// ---------------- stage 3: exact stable descending rank + fused x gather ----------------
__global__ void rank_kernel(const float* __restrict__ scores,
                            const int* __restrict__ batch,
                            const float* __restrict__ x,
                            unsigned* __restrict__ permw,
                            float* __restrict__ out_x,
                            float* __restrict__ out_batch,
                            float* __restrict__ out_perm) {
    int t = threadIdx.x, wave = t >> 6, lane = t & 63;
    int n = blockIdx.x * 4 + wave;       // 1024 blocks x 4 waves
    float s = scores[n];
    const float4* sc4 = (const float4*)scores;
    int r = 0;
    #pragma unroll
    for (int i = 0; i < 16; ++i) {
        int q = lane + (i << 6);         // float4 index, coalesced, cache-resident
        float4 v = sc4[q];
        int m = q << 2;
        r += (v.x > s) || (v.x == s && (m + 0) < n);
        r += (v.y > s) || (v.y == s && (m + 1) < n);
        r += (v.z > s) || (v.z == s && (m + 2) < n);
        r += (v.w > s) || (v.w == s && (m + 3) < n);
    }
    #pragma unroll
    for (int off = 32; off; off >>= 1) r += __shfl_down(r, off);
    r = __shfl(r, 0);                    // broadcast rank to all lanes
    if (r < K_SEL) {
        if (lane == 0) {
            permw[r] = (unsigned)n;
            out_perm[r] = (float)n;
            out_batch[r] = (float)batch[n];
        }
        // whole wave copies the selected x row: 512 floats = 128 float4
        const float4* xs = (const float4*)(x + (size_t)n * D_FEAT);
        float4* od = (float4*)(out_x + (size_t)r * D_FEAT);
        od[lane] = xs[lane];
        od[lane + 64] = xs[lane + 64];
    }
}

// ---------------- stage 4: 2-hop boolean adjacency among selected nodes ----------------
__global__ void adj_kernel(const unsigned* __restrict__ permw,
                           const unsigned* __restrict__ cnt,
                           const unsigned* __restrict__ slots,
                           const unsigned* __restrict__ B,
                           float* __restrict__ out_adj) {
    __shared__ unsigned nbr[MAXDEG];
    __shared__ unsigned rowH[2][NWORDS];
    int p = blockIdx.x, t = threadIdx.x;   // 256 threads
    unsigned n = permw[p];
    unsigned d = min(cnt[n], (unsigned)MAXDEG);
    if (t < (int)d) nbr[t] = slots[((size_t)n << 7) + t] & 0xFFFu;
    __syncthreads();
    int w = t & 127, h = t >> 7;
    unsigned acc = 0;
    for (unsigned i = (unsigned)h; i < d; i += 2)
        acc |= B[((size_t)nbr[i] << 7) + w];   // 512B coalesced rows, L2-resident
    rowH[h][w] = acc;
    __syncthreads();
    if (t < NWORDS) rowH[0][t] |= rowH[1][t];
    __syncthreads();
    float4* o4 = (float4*)(out_adj + (size_t)p * K_SEL);
    #pragma unroll
    for (int i = 0; i < 2; ++i) {
        int q4 = t + (i << 8);             // 512 float4 per row
        int q = q4 << 2;
        unsigned c0 = permw[q], c1 = permw[q + 1], c2 = permw[q + 2], c3 = permw[q + 3];
        float4 v;
        v.x = (float)((rowH[0][c0 >> 5] >> (c0 & 31)) & 1u);
        v.y = (float)((rowH[0][c1 >> 5] >> (c1 & 31)) & 1u);
        v.z = (float)((rowH[0][c2 >> 5] >> (c2 & 31)) & 1u);
        v.w = (float)((rowH[0][c3 >> 5] >> (c3 & 31)) & 1u);
        o4[q4] = v;
    }
}

extern "C" void kernel_launch(void* const* d_in, const int* in_sizes, int n_in,
                              void* d_out, int out_size, void* d_ws, size_t ws_size,
                              hipStream_t stream) {
    const float* x     = (const float*)d_in[0];
    const int*   eidx  = (const int*)d_in[1];
    const float* att   = (const float*)d_in[2];
    const int*   batch = (const int*)d_in[3];
    const int*   dir_p = (const int*)d_in[4];
    const int* src = eidx;
    const int* dst = eidx + N_EDGES;

    // workspace layout (bytes)
    char* ws = (char*)d_ws;
    unsigned* B      = (unsigned*)(ws + 0);        // 4096*128*4 = 2,097,152
    unsigned* cnt    = (unsigned*)(ws + 2097152);  // 16,384
    float*    scores = (float*)   (ws + 2113536);  // 16,384
    unsigned* permw  = (unsigned*)(ws + 2129920);  // 8,192
    unsigned* slots  = (unsigned*)(ws + 2138112);  // 2,097,152 (end ~4.24 MB)

    // output layout (floats)
    float* out_x     = (float*)d_out;                          // 2048*512
    float* out_adj   = out_x + (size_t)K_SEL * D_FEAT;         // 2048*2048
    float* out_batch = out_adj + (size_t)K_SEL * K_SEL;        // 2048
    float* out_perm  = out_batch + K_SEL;                      // 2048

    zero_cnt<<<N_NODES / 256, 256, 0, stream>>>(cnt);
    build_kernel<<<N_EDGES / 512, 512, 0, stream>>>(src, dst, cnt, slots);
    score_kernel<<<N_NODES / 4, 256, 0, stream>>>(cnt, slots, att, dir_p, scores, B);
    rank_kernel<<<N_NODES / 4, 256, 0, stream>>>(scores, batch, x, permw,
                                                 out_x, out_batch, out_perm);
    adj_kernel<<<K_SEL, 256, 0, stream>>>(permw, cnt, slots, B, out_adj);
}